// Round 12
// baseline (266.794 us; speedup 1.0000x reference)
//
#include <hip/hip_runtime.h>
#include <hip/hip_bf16.h>

constexpr int NF = 128;
constexpr int BM = 128;              // rows per gemm12 block
constexpr int SORT_CHUNK = 4096;     // edges per p1 block
constexpr float BN_EPS_C = 1e-5f;

typedef __attribute__((ext_vector_type(8))) short short8;   // 8 bf16 = 4 VGPR
typedef __attribute__((ext_vector_type(4))) float f32x4;    // MFMA acc

__device__ __forceinline__ float asfloat(unsigned int u) {
  union { unsigned int u; float f; } c; c.u = u; return c.f;
}
__device__ __forceinline__ unsigned short f2b(float f) {
  __hip_bfloat16 b = __float2bfloat16(f);           // RNE
  return *reinterpret_cast<unsigned short*>(&b);
}
__device__ __forceinline__ void addbf8(float* acc, uint4 v) {
  acc[0] += asfloat(v.x << 16); acc[1] += asfloat(v.x & 0xffff0000u);
  acc[2] += asfloat(v.y << 16); acc[3] += asfloat(v.y & 0xffff0000u);
  acc[4] += asfloat(v.z << 16); acc[5] += asfloat(v.z & 0xffff0000u);
  acc[6] += asfloat(v.w << 16); acc[7] += asfloat(v.w & 0xffff0000u);
}

// ---------------------------------------------------------------------------
// Fused one-time prep + p1 histogram (all mutually independent work):
//   blocks [0, xBlocks)            : x -> bf16
//   blocks [xBlocks, +wBlocks)     : W1,W2 -> bf16 transposed
//   blocks [.., +B1)               : per-chunk LDS histogram of dst>>8
//   last block                     : ss = identity affine
// ---------------------------------------------------------------------------
__global__ __launch_bounds__(256)
void prep_hist(const float* __restrict__ x, unsigned short* __restrict__ xb,
               long long x4, const float* __restrict__ W1,
               const float* __restrict__ W2, unsigned short* __restrict__ wt,
               float* __restrict__ ss, const int* __restrict__ dst,
               int* __restrict__ ghist, int E, int B1, int nbins1,
               int xBlocks, int wBlocks)
{
  __shared__ int hist[256];
  int bid = blockIdx.x, tid = threadIdx.x;

  if (bid < xBlocks) {
    long long i = (long long)bid * 256 + tid;
    if (i < x4) {
      float4 v = ((const float4*)x)[i];
      ushort4 o;
      o.x = f2b(v.x); o.y = f2b(v.y); o.z = f2b(v.z); o.w = f2b(v.w);
      ((ushort4*)xb)[i] = o;
    }
    return;
  }
  bid -= xBlocks;
  if (bid < wBlocks) {
    int idx = bid * 256 + tid;
    const int half = 3 * 16384;
    if (idx < 2 * half) {
      const float* W = (idx < half) ? W1 : W2;
      int j = (idx < half) ? idx : idx - half;
      int m = j >> 14, ck = j & 16383, c = ck >> 7, k = ck & 127;
      wt[idx] = f2b(W[m * 16384 + k * 128 + c]);
    }
    return;
  }
  bid -= wBlocks;
  if (bid < B1) {
    hist[tid] = 0;
    __syncthreads();
    int base = bid * SORT_CHUNK;
    int end_ = min(E, base + SORT_CHUNK);
    for (int i = base + tid; i < end_; i += 256)
      atomicAdd(&hist[dst[i] >> 8], 1);        // LDS atomic
    __syncthreads();
    if (tid < nbins1) ghist[tid * B1 + bid] = hist[tid];
    return;
  }
  // last block: identity affine for layer-0 gather
  ss[tid] = (tid < NF) ? 1.f : 0.f;
}

// ---------------------------------------------------------------------------
// Single-block exclusive scan over ghist (nscan ~ 38k): serial per-thread
// chunks + Hillis-Steele over 1024 partials. Replaces scan1/scan2/scan_add.
// ---------------------------------------------------------------------------
__global__ __launch_bounds__(1024)
void scan_all(const int* __restrict__ in, int* __restrict__ out, int n)
{
  __shared__ int ls[1024];
  int t = threadIdx.x;
  int chunk = (n + 1023) >> 10;
  int b0 = t * chunk, b1 = min(n, b0 + chunk);
  int s = 0;
  for (int i = b0; i < b1; ++i) s += in[i];
  ls[t] = s;
  __syncthreads();
  #pragma unroll
  for (int d = 1; d < 1024; d <<= 1) {
    int v = (t >= d) ? ls[t - d] : 0;
    __syncthreads();
    ls[t] += v;
    __syncthreads();
  }
  int pre = ls[t] - s;                         // exclusive prefix of this chunk
  for (int i = b0; i < b1; ++i) { int v = in[i]; out[i] = pre; pre += v; }
}

// ---------------------------------------------------------------------------
// CSR build phase 2 (verified rounds 9-11). tmp packed: src<<8 | (dst&255).
// ---------------------------------------------------------------------------
__global__ __launch_bounds__(256)
void p1_scatter(const int* __restrict__ src, const int* __restrict__ dst,
                const int* __restrict__ goff, unsigned* __restrict__ tmp,
                int E, int B1, int nbins1)
{
  __shared__ int cur[256];
  int tid = threadIdx.x, blk = blockIdx.x;
  if (tid < nbins1) cur[tid] = goff[tid * B1 + blk];
  __syncthreads();
  int base = blk * SORT_CHUNK;
  int end_ = min(E, base + SORT_CHUNK);
  for (int i = base + tid; i < end_; i += 256) {
    int d = dst[i];
    int pos = atomicAdd(&cur[d >> 8], 1);      // LDS atomic
    tmp[pos] = ((unsigned)src[i] << 8) | (unsigned)(d & 255);
  }
}

__global__ __launch_bounds__(256)
void p2_sort(const unsigned* __restrict__ tmp, const int* __restrict__ goff,
             int* __restrict__ adj, int* __restrict__ row_off,
             int E, int B1, int nbins1, int N)
{
  __shared__ int hist[256], s[256], cur[256];
  int H = blockIdx.x, tid = threadIdx.x;
  int base = goff[H * B1];
  int end_ = (H + 1 < nbins1) ? goff[(H + 1) * B1] : E;

  hist[tid] = 0;
  __syncthreads();
  for (int i = base + tid; i < end_; i += 256)
    atomicAdd(&hist[(int)(tmp[i] & 255u)], 1); // LDS atomic
  __syncthreads();
  int v = hist[tid];
  s[tid] = v;
  __syncthreads();
  #pragma unroll
  for (int d = 1; d < 256; d <<= 1) {
    int t = (tid >= d) ? s[tid - d] : 0;
    __syncthreads();
    s[tid] += t;
    __syncthreads();
  }
  int excl = s[tid] - v;
  cur[tid] = base + excl;
  int node = H * 256 + tid;
  if (node < N)  row_off[node] = base + excl;
  if (node == N) row_off[N] = E;
  if (H == 0 && tid == 0 && (N & 255) == 0) row_off[N] = E;
  __syncthreads();
  for (int i = base + tid; i < end_; i += 256) {
    unsigned p = tmp[i];
    int pos = atomicAdd(&cur[(int)(p & 255u)], 1);   // LDS atomic
    adj[pos] = (int)(p >> 8);
  }
}

// ---------------------------------------------------------------------------
// Gather + fused BN affine of the previous layer (verified rounds 8-11).
// ---------------------------------------------------------------------------
__global__ __launch_bounds__(256)
void gather_bn(const unsigned short* __restrict__ h, const int* __restrict__ row_off,
               const int* __restrict__ adj, const float* __restrict__ ss,
               unsigned short* __restrict__ agg, int n)
{
  int wv  = threadIdx.x >> 6;
  int l   = threadIdx.x & 63;
  int sub = l >> 4, llo = l & 15;
  int node = blockIdx.x * 4 + wv;
  if (node >= n) return;
  int beg = row_off[node], end = row_off[node + 1];

  float acc[8] = {0.f, 0.f, 0.f, 0.f, 0.f, 0.f, 0.f, 0.f};
  if (sub == 0)
    addbf8(acc, *(const uint4*)(h + (size_t)node * NF + llo * 8));   // self term

  int e = beg + sub;
  for (; e + 12 < end; e += 16) {
    int s0 = adj[e], s1 = adj[e + 4], s2 = adj[e + 8], s3 = adj[e + 12];
    uint4 v0 = *(const uint4*)(h + (size_t)s0 * NF + llo * 8);
    uint4 v1 = *(const uint4*)(h + (size_t)s1 * NF + llo * 8);
    uint4 v2 = *(const uint4*)(h + (size_t)s2 * NF + llo * 8);
    uint4 v3 = *(const uint4*)(h + (size_t)s3 * NF + llo * 8);
    addbf8(acc, v0); addbf8(acc, v1); addbf8(acc, v2); addbf8(acc, v3);
  }
  for (; e < end; e += 4)
    addbf8(acc, *(const uint4*)(h + (size_t)adj[e] * NF + llo * 8));

  #pragma unroll
  for (int j = 0; j < 8; ++j) {
    acc[j] += __shfl_xor(acc[j], 16, 64);
    acc[j] += __shfl_xor(acc[j], 32, 64);
  }

  if (sub == 0) {
    float dp1 = (float)(end - beg + 1);
    unsigned short r[8];
    #pragma unroll
    for (int j = 0; j < 8; ++j) {
      float sc = ss[llo * 8 + j];
      float sh = ss[NF + llo * 8 + j];
      r[j] = f2b(fmaf(acc[j], sc, dp1 * sh));
    }
    uint4 o;
    o.x = (unsigned)r[0] | ((unsigned)r[1] << 16);
    o.y = (unsigned)r[2] | ((unsigned)r[3] << 16);
    o.z = (unsigned)r[4] | ((unsigned)r[5] << 16);
    o.w = (unsigned)r[6] | ((unsigned)r[7] << 16);
    *(uint4*)(agg + (size_t)node * NF + llo * 8) = o;
  }
}

// ---------------------------------------------------------------------------
// Fused MLP via MFMA bf16, BM=128, half-staged Wlds (verified round 11).
// ---------------------------------------------------------------------------
template<bool LAST>
__global__ __launch_bounds__(256)
void gemm12(const unsigned short* __restrict__ agg,
            const unsigned short* __restrict__ w1t, const float* __restrict__ b1,
            const unsigned short* __restrict__ w2t, const float* __restrict__ b2,
            float* __restrict__ vout, unsigned short* __restrict__ vb16,
            double* __restrict__ part, int nrows, int nblk)
{
  __shared__ __align__(16) unsigned short Alds[BM * NF];   // 32 KB
  __shared__ __align__(16) unsigned short Wlds[64 * NF];   // 16 KB (one half)

  const int tid = threadIdx.x;
  const int wid = tid >> 6;        // 0..3
  const int l   = tid & 63;
  const int lhi = l >> 4;          // 0..3
  const int llo = l & 15;          // 0..15
  const int row0 = blockIdx.x * BM;

  // ---- stage A tile (bf16, swizzled): 2048 uint4, 8/thread ----
  #pragma unroll
  for (int i = 0; i < 8; ++i) {
    int fidx = tid + 256 * i;
    int r = fidx >> 4, c16 = fidx & 15;
    int grow = row0 + r;
    uint4 v = make_uint4(0u, 0u, 0u, 0u);
    if (grow < nrows) v = *(const uint4*)(agg + (size_t)grow * NF + c16 * 8);
    int off = r * 256 + ((c16 * 16) ^ ((r & 7) << 4));
    *(uint4*)((char*)Alds + off) = v;
  }

  float b1v[8], b2v[8];
  #pragma unroll
  for (int c = 0; c < 8; ++c) {
    b1v[c] = b1[c * 16 + llo];
    b2v[c] = b2[c * 16 + llo];
  }

  f32x4 acc[2][8];
  #pragma unroll
  for (int s = 0; s < 2; ++s)
    #pragma unroll
    for (int c = 0; c < 8; ++c) acc[s][c] = (f32x4){0.f, 0.f, 0.f, 0.f};

  __syncthreads();                 // A tile visible

  // ---- hoist GEMM1 A-frags to registers ----
  short8 af[4][2];
  #pragma unroll
  for (int t = 0; t < 4; ++t)
    #pragma unroll
    for (int s = 0; s < 2; ++s) {
      int r = wid * 32 + s * 16 + llo;
      int off = r * 256 + ((t * 64 + lhi * 16) ^ ((r & 7) << 4));
      af[t][s] = *(const short8*)((const char*)Alds + off);
    }

  // ---- GEMM1: two 64-col halves of W1^T through Wlds ----
  #pragma unroll
  for (int h = 0; h < 2; ++h) {
    if (h) __syncthreads();        // previous half's readers done
    #pragma unroll
    for (int i = 0; i < 4; ++i) {  // 1024 uint4, 4/thread
      int fidx = tid + 256 * i;
      int wr = fidx >> 4, c16 = fidx & 15;
      uint4 v = *(const uint4*)(w1t + (size_t)(h * 64 + wr) * NF + c16 * 8);
      int off = wr * 256 + ((c16 * 16) ^ ((wr & 7) << 4));
      *(uint4*)((char*)Wlds + off) = v;
    }
    __syncthreads();
    #pragma unroll
    for (int t = 0; t < 4; ++t)
      #pragma unroll
      for (int cl = 0; cl < 4; ++cl) {
        int wr = cl * 16 + llo;
        int off = wr * 256 + ((t * 64 + lhi * 16) ^ ((wr & 7) << 4));
        short8 bf = *(const short8*)((const char*)Wlds + off);
        acc[0][h * 4 + cl] = __builtin_amdgcn_mfma_f32_16x16x32_bf16(af[t][0], bf, acc[0][h * 4 + cl], 0, 0, 0);
        acc[1][h * 4 + cl] = __builtin_amdgcn_mfma_f32_16x16x32_bf16(af[t][1], bf, acc[1][h * 4 + cl], 0, 0, 0);
      }
  }

  // ---- u = relu(acc+b1) -> Alds (each wave writes its own 32 rows) ----
  #pragma unroll
  for (int s = 0; s < 2; ++s)
    #pragma unroll
    for (int c = 0; c < 8; ++c) {
      int colg = c * 16 + llo;
      #pragma unroll
      for (int q = 0; q < 4; ++q) {
        int r = wid * 32 + s * 16 + lhi * 4 + q;
        float u = fmaxf(acc[s][c][q] + b1v[c], 0.f);
        int off = r * 256 + ((colg * 2) ^ ((r & 7) << 4));
        *(unsigned short*)((char*)Alds + off) = f2b(u);
      }
    }
  #pragma unroll
  for (int s = 0; s < 2; ++s)
    #pragma unroll
    for (int c = 0; c < 8; ++c) acc[s][c] = (f32x4){0.f, 0.f, 0.f, 0.f};

  // ---- GEMM2: two halves of W2^T; reload A-frags from u (intra-wave) ----
  #pragma unroll
  for (int h = 0; h < 2; ++h) {
    __syncthreads();               // prior Wlds readers done
    #pragma unroll
    for (int i = 0; i < 4; ++i) {
      int fidx = tid + 256 * i;
      int wr = fidx >> 4, c16 = fidx & 15;
      uint4 v = *(const uint4*)(w2t + (size_t)(h * 64 + wr) * NF + c16 * 8);
      int off = wr * 256 + ((c16 * 16) ^ ((wr & 7) << 4));
      *(uint4*)((char*)Wlds + off) = v;
    }
    __syncthreads();
    if (h == 0) {
      #pragma unroll
      for (int t = 0; t < 4; ++t)
        #pragma unroll
        for (int s = 0; s < 2; ++s) {
          int r = wid * 32 + s * 16 + llo;
          int off = r * 256 + ((t * 64 + lhi * 16) ^ ((r & 7) << 4));
          af[t][s] = *(const short8*)((const char*)Alds + off);
        }
    }
    #pragma unroll
    for (int t = 0; t < 4; ++t)
      #pragma unroll
      for (int cl = 0; cl < 4; ++cl) {
        int wr = cl * 16 + llo;
        int off = wr * 256 + ((t * 64 + lhi * 16) ^ ((wr & 7) << 4));
        short8 bf = *(const short8*)((const char*)Wlds + off);
        acc[0][h * 4 + cl] = __builtin_amdgcn_mfma_f32_16x16x32_bf16(af[t][0], bf, acc[0][h * 4 + cl], 0, 0, 0);
        acc[1][h * 4 + cl] = __builtin_amdgcn_mfma_f32_16x16x32_bf16(af[t][1], bf, acc[1][h * 4 + cl], 0, 0, 0);
      }
  }

  // ---- epilogue: v = relu(acc+b2); store; fp32 lane stats ----
  float ts[8] = {0.f, 0.f, 0.f, 0.f, 0.f, 0.f, 0.f, 0.f};
  float tq[8] = {0.f, 0.f, 0.f, 0.f, 0.f, 0.f, 0.f, 0.f};
  #pragma unroll
  for (int s = 0; s < 2; ++s)
    #pragma unroll
    for (int c = 0; c < 8; ++c) {
      int colg = c * 16 + llo;
      #pragma unroll
      for (int q = 0; q < 4; ++q) {
        int rloc = wid * 32 + s * 16 + lhi * 4 + q;
        int row = row0 + rloc;
        if (row < nrows) {
          float vv = fmaxf(acc[s][c][q] + b2v[c], 0.f);
          ts[c] += vv; tq[c] += vv * vv;
          if (LAST) vout[(size_t)row * NF + colg] = vv;
          else      vb16[(size_t)row * NF + colg] = f2b(vv);
        }
      }
    }

  __syncthreads();                 // all LDS reads done; Alds -> fp64 scratch
  double* redS = (double*)Alds;    // [16][128]
  double* redQ = redS + 16 * NF;   // [16][128]
  int prow = wid * 4 + lhi;
  #pragma unroll
  for (int c = 0; c < 8; ++c) {
    redS[prow * NF + c * 16 + llo] = (double)ts[c];
    redQ[prow * NF + c * 16 + llo] = (double)tq[c];
  }
  __syncthreads();
  if (tid < NF) {
    double s = 0.0;
    #pragma unroll
    for (int r = 0; r < 16; ++r) s += redS[r * NF + tid];
    part[(size_t)blockIdx.x * NF + tid] = s;
  } else {
    int c = tid - NF;
    double s = 0.0;
    #pragma unroll
    for (int r = 0; r < 16; ++r) s += redQ[r * NF + c];
    part[(size_t)nblk * NF + (size_t)blockIdx.x * NF + c] = s;
  }
}

// ---------------------------------------------------------------------------
// BN finalize (verified): 8 blocks x 1024 thr, fixed-order fp64 tree.
// ---------------------------------------------------------------------------
__global__ __launch_bounds__(1024)
void bn_stats_final(const double* __restrict__ part,
                    const float* __restrict__ gamma,
                    const float* __restrict__ beta,
                    float* __restrict__ ss, int nrows, int nblk)
{
  __shared__ double redS[64][17], redQ[64][17];
  int cl  = threadIdx.x & 15;
  int seg = threadIdx.x >> 4;
  int c = blockIdx.x * 16 + cl;
  double s = 0.0, s2 = 0.0;
  for (int b = seg; b < nblk; b += 64) {
    s  += part[(size_t)b * NF + c];
    s2 += part[(size_t)nblk * NF + (size_t)b * NF + c];
  }
  redS[seg][cl] = s;
  redQ[seg][cl] = s2;
  __syncthreads();
  #pragma unroll
  for (int d = 32; d >= 1; d >>= 1) {
    if (seg < d) {
      redS[seg][cl] += redS[seg + d][cl];
      redQ[seg][cl] += redQ[seg + d][cl];
    }
    __syncthreads();
  }
  if (seg == 0) {
    double invN = 1.0 / (double)nrows;
    double mu  = redS[0][cl] * invN;
    double var = redQ[0][cl] * invN - mu * mu;
    double sc  = (double)gamma[c] / sqrt(var + (double)BN_EPS_C);
    ss[c]      = (float)sc;
    ss[NF + c] = (float)((double)beta[c] - mu * sc);
  }
}

// ---------------------------------------------------------------------------
// Final BN apply (in-place) + batch copy, one kernel.
// ---------------------------------------------------------------------------
__global__ __launch_bounds__(256)
void bn_apply_batch(const float* __restrict__ v, const float* __restrict__ ss,
                    float* __restrict__ out, const int* __restrict__ batch,
                    float* __restrict__ outBatch, int nrows)
{
  long long i = (long long)blockIdx.x * 256 + threadIdx.x;
  long long total = (long long)nrows * (NF / 4);
  if (i < total) {
    int c = (int)(i & 31) * 4;
    float4 val = ((const float4*)v)[i];
    float4 o;
    o.x = fmaf(val.x, ss[c + 0], ss[NF + c + 0]);
    o.y = fmaf(val.y, ss[c + 1], ss[NF + c + 1]);
    o.z = fmaf(val.z, ss[c + 2], ss[NF + c + 2]);
    o.w = fmaf(val.w, ss[c + 3], ss[NF + c + 3]);
    ((float4*)out)[i] = o;
  } else {
    long long j = i - total;
    if (j < nrows) outBatch[j] = (float)batch[j];
  }
}

// ---------------------------------------------------------------------------
extern "C" void kernel_launch(void* const* d_in, const int* in_sizes, int n_in,
                              void* d_out, int out_size, void* d_ws, size_t ws_size,
                              hipStream_t stream)
{
  const float* x     = (const float*)d_in[0];
  const int*   ei    = (const int*)  d_in[1];
  const int*   batch = (const int*)  d_in[2];
  const float* W1    = (const float*)d_in[3];
  const float* b1    = (const float*)d_in[4];
  const float* W2    = (const float*)d_in[5];
  const float* b2    = (const float*)d_in[6];
  const float* gamma = (const float*)d_in[7];
  const float* beta  = (const float*)d_in[8];

  const int N = in_sizes[2];
  const int E = in_sizes[1] / 2;
  const int L = in_sizes[4] / NF;

  const int* src = ei;
  const int* dst = ei + E;

  const int nblk   = (N + BM - 1) / BM;
  const int B1     = (E + SORT_CHUNK - 1) / SORT_CHUNK;
  const int nbins1 = (N + 255) >> 8;
  const int nscan  = nbins1 * B1;

  // workspace layout
  double* part = (double*)d_ws;                                 // 2*nblk*128
  float*  ss   = (float*)(part + 2 * (size_t)nblk * NF);        // 256
  unsigned short* aggb = (unsigned short*)(ss + 256);           // N*128 bf16
  unsigned short* vb   = aggb + (size_t)N * NF;                 // N*128 bf16
  unsigned short* wt   = vb + (size_t)N * NF;                   // 6*16384 bf16
  int* row_off = (int*)(wt + 6 * 16384);                        // N+1
  int* adj     = row_off + (N + 1);                             // E
  // CSR-build temporaries overlap layer buffers (build precedes first use):
  unsigned* tmp = (unsigned*)aggb;                              // E uints
  int*  ghist = (int*)vb;                                       // nscan
  int*  goff  = ghist + nscan;                                  // nscan

  float* vbuf = (float*)d_out;                                  // N*128 fp32 (final)
  float* outBatch = vbuf + (size_t)N * NF;
  unsigned short* xb = (unsigned short*)vbuf;                   // N*128 bf16 (temp)

  const long long x4 = (long long)N * NF / 4;
  const long long bnTot = (long long)N * (NF / 4) + N;
  const int xBlocks = (int)((x4 + 255) / 256);
  const int wBlocks = (6 * 16384 + 255) / 256;

  // ---- fused prep (x/W converts, ss init, p1 histogram): 1 launch ----
  prep_hist<<<xBlocks + wBlocks + B1 + 1, 256, 0, stream>>>(
      x, xb, x4, W1, W2, wt, ss, dst, ghist, E, B1, nbins1, xBlocks, wBlocks);

  // ---- CSR build: scan + scatter + sort ----
  scan_all<<<1, 1024, 0, stream>>>(ghist, goff, nscan);
  p1_scatter<<<B1, 256, 0, stream>>>(src, dst, goff, tmp, E, B1, nbins1);
  p2_sort<<<nbins1, 256, 0, stream>>>(tmp, goff, adj, row_off, E, B1, nbins1, N);

  // ---- layers ----
  for (int ly = 0; ly < L; ++ly) {
    const unsigned short* hsrc = (ly == 0) ? xb : vb;
    gather_bn<<<(N + 3) / 4, 256, 0, stream>>>(hsrc, row_off, adj, ss, aggb, N);

    const unsigned short* w1t = wt + (size_t)ly * 16384;
    const unsigned short* w2t = wt + (size_t)(3 + ly) * 16384;
    if (ly == L - 1)
      gemm12<true><<<nblk, 256, 0, stream>>>(aggb, w1t, b1 + ly * NF, w2t, b2 + ly * NF,
                                             vbuf, vb, part, N, nblk);
    else
      gemm12<false><<<nblk, 256, 0, stream>>>(aggb, w1t, b1 + ly * NF, w2t, b2 + ly * NF,
                                              vbuf, vb, part, N, nblk);
    bn_stats_final<<<8, 1024, 0, stream>>>(part, gamma + ly * NF, beta + ly * NF,
                                           ss, N, nblk);
  }

  // final: h = BN(v) in place + batch copy
  bn_apply_batch<<<(int)((bnTot + 255) / 256), 256, 0, stream>>>(
      vbuf, ss, vbuf, batch, outBatch, N);
}

// Round 13
// 218.903 us; speedup vs baseline: 1.2188x; 1.2188x over previous
//
#include <hip/hip_runtime.h>
#include <hip/hip_bf16.h>

constexpr int NF = 128;
constexpr int BM = 128;              // rows per gemm12 block
constexpr int SORT_CHUNK = 4096;     // edges per p1 block
constexpr float BN_EPS_C = 1e-5f;

typedef __attribute__((ext_vector_type(8))) short short8;   // 8 bf16 = 4 VGPR
typedef __attribute__((ext_vector_type(4))) float f32x4;    // MFMA acc

__device__ __forceinline__ float asfloat(unsigned int u) {
  union { unsigned int u; float f; } c; c.u = u; return c.f;
}
__device__ __forceinline__ unsigned short f2b(float f) {
  __hip_bfloat16 b = __float2bfloat16(f);           // RNE
  return *reinterpret_cast<unsigned short*>(&b);
}
__device__ __forceinline__ void addbf8(float* acc, uint4 v) {
  acc[0] += asfloat(v.x << 16); acc[1] += asfloat(v.x & 0xffff0000u);
  acc[2] += asfloat(v.y << 16); acc[3] += asfloat(v.y & 0xffff0000u);
  acc[4] += asfloat(v.z << 16); acc[5] += asfloat(v.z & 0xffff0000u);
  acc[6] += asfloat(v.w << 16); acc[7] += asfloat(v.w & 0xffff0000u);
}

// ---------------------------------------------------------------------------
// Fused one-time prep + p1 histogram (verified round 12):
//   blocks [0, xBlocks)            : x -> bf16
//   blocks [xBlocks, +wBlocks)     : W1,W2 -> bf16 transposed
//   blocks [.., +B1)               : per-chunk LDS histogram of dst>>8
//   last block                     : ss = identity affine
// ---------------------------------------------------------------------------
__global__ __launch_bounds__(256)
void prep_hist(const float* __restrict__ x, unsigned short* __restrict__ xb,
               long long x4, const float* __restrict__ W1,
               const float* __restrict__ W2, unsigned short* __restrict__ wt,
               float* __restrict__ ss, const int* __restrict__ dst,
               int* __restrict__ ghist, int E, int B1, int nbins1,
               int xBlocks, int wBlocks)
{
  __shared__ int hist[256];
  int bid = blockIdx.x, tid = threadIdx.x;

  if (bid < xBlocks) {
    long long i = (long long)bid * 256 + tid;
    if (i < x4) {
      float4 v = ((const float4*)x)[i];
      ushort4 o;
      o.x = f2b(v.x); o.y = f2b(v.y); o.z = f2b(v.z); o.w = f2b(v.w);
      ((ushort4*)xb)[i] = o;
    }
    return;
  }
  bid -= xBlocks;
  if (bid < wBlocks) {
    int idx = bid * 256 + tid;
    const int half = 3 * 16384;
    if (idx < 2 * half) {
      const float* W = (idx < half) ? W1 : W2;
      int j = (idx < half) ? idx : idx - half;
      int m = j >> 14, ck = j & 16383, c = ck >> 7, k = ck & 127;
      wt[idx] = f2b(W[m * 16384 + k * 128 + c]);
    }
    return;
  }
  bid -= wBlocks;
  if (bid < B1) {
    hist[tid] = 0;
    __syncthreads();
    int base = bid * SORT_CHUNK;
    int end_ = min(E, base + SORT_CHUNK);
    for (int i = base + tid; i < end_; i += 256)
      atomicAdd(&hist[dst[i] >> 8], 1);        // LDS atomic
    __syncthreads();
    if (tid < nbins1) ghist[tid * B1 + bid] = hist[tid];
    return;
  }
  // last block: identity affine for layer-0 gather
  ss[tid] = (tid < NF) ? 1.f : 0.f;
}

// ---------------------------------------------------------------------------
// Exclusive scan chain (verified rounds 9-11): chunk scan + chunk-total scan
// + offset add. Parallel across CUs — do NOT single-block this (round-12
// lesson: 1-block scan = 56 µs of single-CU latency serialization).
// ---------------------------------------------------------------------------
__global__ __launch_bounds__(256)
void scan1(const int* __restrict__ count, int* __restrict__ excl,
           int* __restrict__ bsum, int n)
{
  __shared__ int s[256];
  int tid = threadIdx.x;
  int i = blockIdx.x * 256 + tid;
  int v = (i < n) ? count[i] : 0;
  s[tid] = v;
  __syncthreads();
  #pragma unroll
  for (int d = 1; d < 256; d <<= 1) {
    int t = (tid >= d) ? s[tid - d] : 0;
    __syncthreads();
    s[tid] += t;
    __syncthreads();
  }
  if (i < n) excl[i] = s[tid] - v;
  if (tid == 255) bsum[blockIdx.x] = s[255];
}

__global__ __launch_bounds__(256)
void scan2(int* __restrict__ bsum, int nb)
{
  __shared__ int s[256];
  int tid = threadIdx.x;
  int v = (tid < nb) ? bsum[tid] : 0;
  s[tid] = v;
  __syncthreads();
  #pragma unroll
  for (int d = 1; d < 256; d <<= 1) {
    int t = (tid >= d) ? s[tid - d] : 0;
    __syncthreads();
    s[tid] += t;
    __syncthreads();
  }
  if (tid < nb) bsum[tid] = s[tid] - v;
}

__global__ __launch_bounds__(256)
void scan_add(int* __restrict__ data, const int* __restrict__ bsum, int n)
{
  int i = blockIdx.x * 256 + threadIdx.x;
  if (i < n) data[i] += bsum[blockIdx.x];
}

// ---------------------------------------------------------------------------
// CSR build phase 2 (verified rounds 9-12). tmp packed: src<<8 | (dst&255).
// ---------------------------------------------------------------------------
__global__ __launch_bounds__(256)
void p1_scatter(const int* __restrict__ src, const int* __restrict__ dst,
                const int* __restrict__ goff, unsigned* __restrict__ tmp,
                int E, int B1, int nbins1)
{
  __shared__ int cur[256];
  int tid = threadIdx.x, blk = blockIdx.x;
  if (tid < nbins1) cur[tid] = goff[tid * B1 + blk];
  __syncthreads();
  int base = blk * SORT_CHUNK;
  int end_ = min(E, base + SORT_CHUNK);
  for (int i = base + tid; i < end_; i += 256) {
    int d = dst[i];
    int pos = atomicAdd(&cur[d >> 8], 1);      // LDS atomic
    tmp[pos] = ((unsigned)src[i] << 8) | (unsigned)(d & 255);
  }
}

__global__ __launch_bounds__(256)
void p2_sort(const unsigned* __restrict__ tmp, const int* __restrict__ goff,
             int* __restrict__ adj, int* __restrict__ row_off,
             int E, int B1, int nbins1, int N)
{
  __shared__ int hist[256], s[256], cur[256];
  int H = blockIdx.x, tid = threadIdx.x;
  int base = goff[H * B1];
  int end_ = (H + 1 < nbins1) ? goff[(H + 1) * B1] : E;

  hist[tid] = 0;
  __syncthreads();
  for (int i = base + tid; i < end_; i += 256)
    atomicAdd(&hist[(int)(tmp[i] & 255u)], 1); // LDS atomic
  __syncthreads();
  int v = hist[tid];
  s[tid] = v;
  __syncthreads();
  #pragma unroll
  for (int d = 1; d < 256; d <<= 1) {
    int t = (tid >= d) ? s[tid - d] : 0;
    __syncthreads();
    s[tid] += t;
    __syncthreads();
  }
  int excl = s[tid] - v;
  cur[tid] = base + excl;
  int node = H * 256 + tid;
  if (node < N)  row_off[node] = base + excl;
  if (node == N) row_off[N] = E;
  if (H == 0 && tid == 0 && (N & 255) == 0) row_off[N] = E;
  __syncthreads();
  for (int i = base + tid; i < end_; i += 256) {
    unsigned p = tmp[i];
    int pos = atomicAdd(&cur[(int)(p & 255u)], 1);   // LDS atomic
    adj[pos] = (int)(p >> 8);
  }
}

// ---------------------------------------------------------------------------
// Gather + fused BN affine of the previous layer (verified rounds 8-12).
// ---------------------------------------------------------------------------
__global__ __launch_bounds__(256)
void gather_bn(const unsigned short* __restrict__ h, const int* __restrict__ row_off,
               const int* __restrict__ adj, const float* __restrict__ ss,
               unsigned short* __restrict__ agg, int n)
{
  int wv  = threadIdx.x >> 6;
  int l   = threadIdx.x & 63;
  int sub = l >> 4, llo = l & 15;
  int node = blockIdx.x * 4 + wv;
  if (node >= n) return;
  int beg = row_off[node], end = row_off[node + 1];

  float acc[8] = {0.f, 0.f, 0.f, 0.f, 0.f, 0.f, 0.f, 0.f};
  if (sub == 0)
    addbf8(acc, *(const uint4*)(h + (size_t)node * NF + llo * 8));   // self term

  int e = beg + sub;
  for (; e + 12 < end; e += 16) {
    int s0 = adj[e], s1 = adj[e + 4], s2 = adj[e + 8], s3 = adj[e + 12];
    uint4 v0 = *(const uint4*)(h + (size_t)s0 * NF + llo * 8);
    uint4 v1 = *(const uint4*)(h + (size_t)s1 * NF + llo * 8);
    uint4 v2 = *(const uint4*)(h + (size_t)s2 * NF + llo * 8);
    uint4 v3 = *(const uint4*)(h + (size_t)s3 * NF + llo * 8);
    addbf8(acc, v0); addbf8(acc, v1); addbf8(acc, v2); addbf8(acc, v3);
  }
  for (; e < end; e += 4)
    addbf8(acc, *(const uint4*)(h + (size_t)adj[e] * NF + llo * 8));

  #pragma unroll
  for (int j = 0; j < 8; ++j) {
    acc[j] += __shfl_xor(acc[j], 16, 64);
    acc[j] += __shfl_xor(acc[j], 32, 64);
  }

  if (sub == 0) {
    float dp1 = (float)(end - beg + 1);
    unsigned short r[8];
    #pragma unroll
    for (int j = 0; j < 8; ++j) {
      float sc = ss[llo * 8 + j];
      float sh = ss[NF + llo * 8 + j];
      r[j] = f2b(fmaf(acc[j], sc, dp1 * sh));
    }
    uint4 o;
    o.x = (unsigned)r[0] | ((unsigned)r[1] << 16);
    o.y = (unsigned)r[2] | ((unsigned)r[3] << 16);
    o.z = (unsigned)r[4] | ((unsigned)r[5] << 16);
    o.w = (unsigned)r[6] | ((unsigned)r[7] << 16);
    *(uint4*)(agg + (size_t)node * NF + llo * 8) = o;
  }
}

// ---------------------------------------------------------------------------
// Fused MLP via MFMA bf16, BM=128, half-staged Wlds (verified rounds 11-12).
// ---------------------------------------------------------------------------
template<bool LAST>
__global__ __launch_bounds__(256)
void gemm12(const unsigned short* __restrict__ agg,
            const unsigned short* __restrict__ w1t, const float* __restrict__ b1,
            const unsigned short* __restrict__ w2t, const float* __restrict__ b2,
            float* __restrict__ vout, unsigned short* __restrict__ vb16,
            double* __restrict__ part, int nrows, int nblk)
{
  __shared__ __align__(16) unsigned short Alds[BM * NF];   // 32 KB
  __shared__ __align__(16) unsigned short Wlds[64 * NF];   // 16 KB (one half)

  const int tid = threadIdx.x;
  const int wid = tid >> 6;        // 0..3
  const int l   = tid & 63;
  const int lhi = l >> 4;          // 0..3
  const int llo = l & 15;          // 0..15
  const int row0 = blockIdx.x * BM;

  // ---- stage A tile (bf16, swizzled): 2048 uint4, 8/thread ----
  #pragma unroll
  for (int i = 0; i < 8; ++i) {
    int fidx = tid + 256 * i;
    int r = fidx >> 4, c16 = fidx & 15;
    int grow = row0 + r;
    uint4 v = make_uint4(0u, 0u, 0u, 0u);
    if (grow < nrows) v = *(const uint4*)(agg + (size_t)grow * NF + c16 * 8);
    int off = r * 256 + ((c16 * 16) ^ ((r & 7) << 4));
    *(uint4*)((char*)Alds + off) = v;
  }

  float b1v[8], b2v[8];
  #pragma unroll
  for (int c = 0; c < 8; ++c) {
    b1v[c] = b1[c * 16 + llo];
    b2v[c] = b2[c * 16 + llo];
  }

  f32x4 acc[2][8];
  #pragma unroll
  for (int s = 0; s < 2; ++s)
    #pragma unroll
    for (int c = 0; c < 8; ++c) acc[s][c] = (f32x4){0.f, 0.f, 0.f, 0.f};

  __syncthreads();                 // A tile visible

  // ---- hoist GEMM1 A-frags to registers ----
  short8 af[4][2];
  #pragma unroll
  for (int t = 0; t < 4; ++t)
    #pragma unroll
    for (int s = 0; s < 2; ++s) {
      int r = wid * 32 + s * 16 + llo;
      int off = r * 256 + ((t * 64 + lhi * 16) ^ ((r & 7) << 4));
      af[t][s] = *(const short8*)((const char*)Alds + off);
    }

  // ---- GEMM1: two 64-col halves of W1^T through Wlds ----
  #pragma unroll
  for (int h = 0; h < 2; ++h) {
    if (h) __syncthreads();        // previous half's readers done
    #pragma unroll
    for (int i = 0; i < 4; ++i) {  // 1024 uint4, 4/thread
      int fidx = tid + 256 * i;
      int wr = fidx >> 4, c16 = fidx & 15;
      uint4 v = *(const uint4*)(w1t + (size_t)(h * 64 + wr) * NF + c16 * 8);
      int off = wr * 256 + ((c16 * 16) ^ ((wr & 7) << 4));
      *(uint4*)((char*)Wlds + off) = v;
    }
    __syncthreads();
    #pragma unroll
    for (int t = 0; t < 4; ++t)
      #pragma unroll
      for (int cl = 0; cl < 4; ++cl) {
        int wr = cl * 16 + llo;
        int off = wr * 256 + ((t * 64 + lhi * 16) ^ ((wr & 7) << 4));
        short8 bf = *(const short8*)((const char*)Wlds + off);
        acc[0][h * 4 + cl] = __builtin_amdgcn_mfma_f32_16x16x32_bf16(af[t][0], bf, acc[0][h * 4 + cl], 0, 0, 0);
        acc[1][h * 4 + cl] = __builtin_amdgcn_mfma_f32_16x16x32_bf16(af[t][1], bf, acc[1][h * 4 + cl], 0, 0, 0);
      }
  }

  // ---- u = relu(acc+b1) -> Alds (each wave writes its own 32 rows) ----
  #pragma unroll
  for (int s = 0; s < 2; ++s)
    #pragma unroll
    for (int c = 0; c < 8; ++c) {
      int colg = c * 16 + llo;
      #pragma unroll
      for (int q = 0; q < 4; ++q) {
        int r = wid * 32 + s * 16 + lhi * 4 + q;
        float u = fmaxf(acc[s][c][q] + b1v[c], 0.f);
        int off = r * 256 + ((colg * 2) ^ ((r & 7) << 4));
        *(unsigned short*)((char*)Alds + off) = f2b(u);
      }
    }
  #pragma unroll
  for (int s = 0; s < 2; ++s)
    #pragma unroll
    for (int c = 0; c < 8; ++c) acc[s][c] = (f32x4){0.f, 0.f, 0.f, 0.f};

  // ---- GEMM2: two halves of W2^T; reload A-frags from u (intra-wave) ----
  #pragma unroll
  for (int h = 0; h < 2; ++h) {
    __syncthreads();               // prior Wlds readers done
    #pragma unroll
    for (int i = 0; i < 4; ++i) {
      int fidx = tid + 256 * i;
      int wr = fidx >> 4, c16 = fidx & 15;
      uint4 v = *(const uint4*)(w2t + (size_t)(h * 64 + wr) * NF + c16 * 8);
      int off = wr * 256 + ((c16 * 16) ^ ((wr & 7) << 4));
      *(uint4*)((char*)Wlds + off) = v;
    }
    __syncthreads();
    if (h == 0) {
      #pragma unroll
      for (int t = 0; t < 4; ++t)
        #pragma unroll
        for (int s = 0; s < 2; ++s) {
          int r = wid * 32 + s * 16 + llo;
          int off = r * 256 + ((t * 64 + lhi * 16) ^ ((r & 7) << 4));
          af[t][s] = *(const short8*)((const char*)Alds + off);
        }
    }
    #pragma unroll
    for (int t = 0; t < 4; ++t)
      #pragma unroll
      for (int cl = 0; cl < 4; ++cl) {
        int wr = cl * 16 + llo;
        int off = wr * 256 + ((t * 64 + lhi * 16) ^ ((wr & 7) << 4));
        short8 bf = *(const short8*)((const char*)Wlds + off);
        acc[0][h * 4 + cl] = __builtin_amdgcn_mfma_f32_16x16x32_bf16(af[t][0], bf, acc[0][h * 4 + cl], 0, 0, 0);
        acc[1][h * 4 + cl] = __builtin_amdgcn_mfma_f32_16x16x32_bf16(af[t][1], bf, acc[1][h * 4 + cl], 0, 0, 0);
      }
  }

  // ---- epilogue: v = relu(acc+b2); store; fp32 lane stats ----
  float ts[8] = {0.f, 0.f, 0.f, 0.f, 0.f, 0.f, 0.f, 0.f};
  float tq[8] = {0.f, 0.f, 0.f, 0.f, 0.f, 0.f, 0.f, 0.f};
  #pragma unroll
  for (int s = 0; s < 2; ++s)
    #pragma unroll
    for (int c = 0; c < 8; ++c) {
      int colg = c * 16 + llo;
      #pragma unroll
      for (int q = 0; q < 4; ++q) {
        int rloc = wid * 32 + s * 16 + lhi * 4 + q;
        int row = row0 + rloc;
        if (row < nrows) {
          float vv = fmaxf(acc[s][c][q] + b2v[c], 0.f);
          ts[c] += vv; tq[c] += vv * vv;
          if (LAST) vout[(size_t)row * NF + colg] = vv;
          else      vb16[(size_t)row * NF + colg] = f2b(vv);
        }
      }
    }

  __syncthreads();                 // all LDS reads done; Alds -> fp64 scratch
  double* redS = (double*)Alds;    // [16][128]
  double* redQ = redS + 16 * NF;   // [16][128]
  int prow = wid * 4 + lhi;
  #pragma unroll
  for (int c = 0; c < 8; ++c) {
    redS[prow * NF + c * 16 + llo] = (double)ts[c];
    redQ[prow * NF + c * 16 + llo] = (double)tq[c];
  }
  __syncthreads();
  if (tid < NF) {
    double s = 0.0;
    #pragma unroll
    for (int r = 0; r < 16; ++r) s += redS[r * NF + tid];
    part[(size_t)blockIdx.x * NF + tid] = s;
  } else {
    int c = tid - NF;
    double s = 0.0;
    #pragma unroll
    for (int r = 0; r < 16; ++r) s += redQ[r * NF + c];
    part[(size_t)nblk * NF + (size_t)blockIdx.x * NF + c] = s;
  }
}

// ---------------------------------------------------------------------------
// BN finalize (verified): 8 blocks x 1024 thr, fixed-order fp64 tree.
// ---------------------------------------------------------------------------
__global__ __launch_bounds__(1024)
void bn_stats_final(const double* __restrict__ part,
                    const float* __restrict__ gamma,
                    const float* __restrict__ beta,
                    float* __restrict__ ss, int nrows, int nblk)
{
  __shared__ double redS[64][17], redQ[64][17];
  int cl  = threadIdx.x & 15;
  int seg = threadIdx.x >> 4;
  int c = blockIdx.x * 16 + cl;
  double s = 0.0, s2 = 0.0;
  for (int b = seg; b < nblk; b += 64) {
    s  += part[(size_t)b * NF + c];
    s2 += part[(size_t)nblk * NF + (size_t)b * NF + c];
  }
  redS[seg][cl] = s;
  redQ[seg][cl] = s2;
  __syncthreads();
  #pragma unroll
  for (int d = 32; d >= 1; d >>= 1) {
    if (seg < d) {
      redS[seg][cl] += redS[seg + d][cl];
      redQ[seg][cl] += redQ[seg + d][cl];
    }
    __syncthreads();
  }
  if (seg == 0) {
    double invN = 1.0 / (double)nrows;
    double mu  = redS[0][cl] * invN;
    double var = redQ[0][cl] * invN - mu * mu;
    double sc  = (double)gamma[c] / sqrt(var + (double)BN_EPS_C);
    ss[c]      = (float)sc;
    ss[NF + c] = (float)((double)beta[c] - mu * sc);
  }
}

// ---------------------------------------------------------------------------
// Final BN apply (in-place) + batch copy, one kernel.
// ---------------------------------------------------------------------------
__global__ __launch_bounds__(256)
void bn_apply_batch(const float* __restrict__ v, const float* __restrict__ ss,
                    float* __restrict__ out, const int* __restrict__ batch,
                    float* __restrict__ outBatch, int nrows)
{
  long long i = (long long)blockIdx.x * 256 + threadIdx.x;
  long long total = (long long)nrows * (NF / 4);
  if (i < total) {
    int c = (int)(i & 31) * 4;
    float4 val = ((const float4*)v)[i];
    float4 o;
    o.x = fmaf(val.x, ss[c + 0], ss[NF + c + 0]);
    o.y = fmaf(val.y, ss[c + 1], ss[NF + c + 1]);
    o.z = fmaf(val.z, ss[c + 2], ss[NF + c + 2]);
    o.w = fmaf(val.w, ss[c + 3], ss[NF + c + 3]);
    ((float4*)out)[i] = o;
  } else {
    long long j = i - total;
    if (j < nrows) outBatch[j] = (float)batch[j];
  }
}

// ---------------------------------------------------------------------------
extern "C" void kernel_launch(void* const* d_in, const int* in_sizes, int n_in,
                              void* d_out, int out_size, void* d_ws, size_t ws_size,
                              hipStream_t stream)
{
  const float* x     = (const float*)d_in[0];
  const int*   ei    = (const int*)  d_in[1];
  const int*   batch = (const int*)  d_in[2];
  const float* W1    = (const float*)d_in[3];
  const float* b1    = (const float*)d_in[4];
  const float* W2    = (const float*)d_in[5];
  const float* b2    = (const float*)d_in[6];
  const float* gamma = (const float*)d_in[7];
  const float* beta  = (const float*)d_in[8];

  const int N = in_sizes[2];
  const int E = in_sizes[1] / 2;
  const int L = in_sizes[4] / NF;

  const int* src = ei;
  const int* dst = ei + E;

  const int nblk   = (N + BM - 1) / BM;
  const int B1     = (E + SORT_CHUNK - 1) / SORT_CHUNK;
  const int nbins1 = (N + 255) >> 8;
  const int nscan  = nbins1 * B1;
  const int scanBlocks = (nscan + 255) / 256;

  // workspace layout
  double* part = (double*)d_ws;                                 // 2*nblk*128
  float*  ss   = (float*)(part + 2 * (size_t)nblk * NF);        // 256
  unsigned short* aggb = (unsigned short*)(ss + 256);           // N*128 bf16
  unsigned short* vb   = aggb + (size_t)N * NF;                 // N*128 bf16
  unsigned short* wt   = vb + (size_t)N * NF;                   // 6*16384 bf16
  int* row_off = (int*)(wt + 6 * 16384);                        // N+1
  int* adj     = row_off + (N + 1);                             // E
  // CSR-build temporaries overlap layer buffers (build precedes first use):
  unsigned* tmp = (unsigned*)aggb;                              // E uints
  int*  ghist = (int*)vb;                                       // nscan
  int*  goff  = ghist + nscan;                                  // nscan
  int*  bsum  = goff + nscan;                                   // scanBlocks

  float* vbuf = (float*)d_out;                                  // N*128 fp32 (final)
  float* outBatch = vbuf + (size_t)N * NF;
  unsigned short* xb = (unsigned short*)vbuf;                   // N*128 bf16 (temp)

  const long long x4 = (long long)N * NF / 4;
  const long long bnTot = (long long)N * (NF / 4) + N;
  const int xBlocks = (int)((x4 + 255) / 256);
  const int wBlocks = (6 * 16384 + 255) / 256;

  // ---- fused prep (x/W converts, ss init, p1 histogram): 1 launch ----
  prep_hist<<<xBlocks + wBlocks + B1 + 1, 256, 0, stream>>>(
      x, xb, x4, W1, W2, wt, ss, dst, ghist, E, B1, nbins1, xBlocks, wBlocks);

  // ---- CSR build: parallel scan chain + scatter + sort ----
  scan1<<<scanBlocks, 256, 0, stream>>>(ghist, goff, bsum, nscan);
  scan2<<<1, 256, 0, stream>>>(bsum, scanBlocks);
  scan_add<<<scanBlocks, 256, 0, stream>>>(goff, bsum, nscan);
  p1_scatter<<<B1, 256, 0, stream>>>(src, dst, goff, tmp, E, B1, nbins1);
  p2_sort<<<nbins1, 256, 0, stream>>>(tmp, goff, adj, row_off, E, B1, nbins1, N);

  // ---- layers ----
  for (int ly = 0; ly < L; ++ly) {
    const unsigned short* hsrc = (ly == 0) ? xb : vb;
    gather_bn<<<(N + 3) / 4, 256, 0, stream>>>(hsrc, row_off, adj, ss, aggb, N);

    const unsigned short* w1t = wt + (size_t)ly * 16384;
    const unsigned short* w2t = wt + (size_t)(3 + ly) * 16384;
    if (ly == L - 1)
      gemm12<true><<<nblk, 256, 0, stream>>>(aggb, w1t, b1 + ly * NF, w2t, b2 + ly * NF,
                                             vbuf, vb, part, N, nblk);
    else
      gemm12<false><<<nblk, 256, 0, stream>>>(aggb, w1t, b1 + ly * NF, w2t, b2 + ly * NF,
                                              vbuf, vb, part, N, nblk);
    bn_stats_final<<<8, 1024, 0, stream>>>(part, gamma + ly * NF, beta + ly * NF,
                                           ss, N, nblk);
  }

  // final: h = BN(v) in place + batch copy
  bn_apply_batch<<<(int)((bnTot + 255) / 256), 256, 0, stream>>>(
      vbuf, ss, vbuf, batch, outBatch, N);
}